// Round 3
// baseline (1581.621 us; speedup 1.0000x reference)
//
#include <hip/hip_runtime.h>

typedef _Float16 f16;
typedef _Float16 f16x8 __attribute__((ext_vector_type(8)));
typedef float f32x4 __attribute__((ext_vector_type(4)));

typedef const __attribute__((address_space(1))) void GV;
typedef __attribute__((address_space(3))) void LV;

__device__ __forceinline__ void gload16(const void* g, void* l) {
  __builtin_amdgcn_global_load_lds((GV*)g, (LV*)l, 16, 0, 0);
}

// ---- fragment helpers ----
// [128][32] f16 chunk (8KB), row stride 64B, swizzle ch^=row&3
__device__ __forceinline__ f16x8 frag32(const f16* T, int row, int chunk) {
  int ch = chunk ^ (row & 3);
  return *(const f16x8*)((const char*)T + row * 64 + ch * 16);
}
// [128][64] f16 tile (16KB), row stride 128B, swizzle ch^=row&7 (gemm512 only)
__device__ __forceinline__ f16x8 frag64(const f16* T, int row, int chunk) {
  int ch = chunk ^ (row & 7);
  return *(const f16x8*)((const char*)T + row * 128 + ch * 16);
}
// [128][128] f16 tile (32KB), row stride 256B, full-XOR swizzle
__device__ __forceinline__ f16x8 frag128(const f16* T, int row, int chunk) {
  int ch = chunk ^ (row & 15);
  return *(const f16x8*)((const char*)T + row * 256 + ch * 16);
}
__device__ __forceinline__ f16* elem128(f16* T, int row, int col) {
  return (f16*)((char*)T + row * 256 + (((col >> 3) ^ (row & 15)) << 4) + (col & 7) * 2);
}

#define MFMA(a, b, c) __builtin_amdgcn_mfma_f32_16x16x32_f16(a, b, c, 0, 0, 0)

__device__ __forceinline__ float sigm(float v) { return 1.f / (1.f + __expf(-v)); }
__device__ __forceinline__ float tanhfast(float v) { return 1.f - 2.f / (1.f + __expf(2.f * v)); }

// 4-block group barrier: monotonic counter, agent-scope release/acquire.
__device__ __forceinline__ void group_sync(unsigned* bar, unsigned target) {
  __syncthreads();
  if (threadIdx.x == 0) {
    __hip_atomic_fetch_add(bar, 1u, __ATOMIC_RELEASE, __HIP_MEMORY_SCOPE_AGENT);
    int guard = 0;
    while (__hip_atomic_load(bar, __ATOMIC_ACQUIRE, __HIP_MEMORY_SCOPE_AGENT) < target) {
      __builtin_amdgcn_s_sleep(2);
      if (++guard > 50000000) break;  // safety valve: fail loud, not hang
    }
  }
  __syncthreads();
}

// stage one K-chunk pair (A[128][32] + B[128][32], both ld=512) into sel buffer
__device__ __forceinline__ void stage_pair(const f16* Asrc, const f16* Bsrc, int kt,
                                           char* smbase, int sel, int wid,
                                           size_t offA0, size_t offA1) {
  const f16* ap = Asrc + kt * 32;
  const f16* bp = Bsrc + kt * 32;
  char* d = smbase + sel * 16384 + wid * 1024;
  gload16(ap + offA0, d);
  gload16(ap + offA1, d + 4096);
  gload16(bp + offA0, d + 8192);
  gload16(bp + offA1, d + 12288);
}

// G[node 128][h/k 512-reduce] = A_tile @ B  (B rows = feature, ld 512)
__device__ __forceinline__ void phase1(const f16* Asrc, const f16* Bsrc,
                                       char* smbase, int wid, int wm, int wn,
                                       int g, int r, size_t offA0, size_t offA1,
                                       f32x4 (&acc)[4][4]) {
  stage_pair(Asrc, Bsrc, 0, smbase, 0, wid, offA0, offA1);
  __syncthreads();
  for (int kt = 0; kt < 16; ++kt) {
    int sel = kt & 1;
    if (kt < 15) stage_pair(Asrc, Bsrc, kt + 1, smbase, sel ^ 1, wid, offA0, offA1);
    const f16* Ta = (const f16*)(smbase + sel * 16384);
    const f16* Tb = (const f16*)(smbase + sel * 16384 + 8192);
    f16x8 af[4], bf[4];
#pragma unroll
    for (int i = 0; i < 4; ++i) af[i] = frag32(Ta, wm + i * 16 + r, g);
#pragma unroll
    for (int j = 0; j < 4; ++j) bf[j] = frag32(Tb, wn + j * 16 + r, g);
#pragma unroll
    for (int i = 0; i < 4; ++i)
#pragma unroll
      for (int j = 0; j < 4; ++j)
        acc[i][j] = MFMA(af[i], bf[j], acc[i][j]);
    __syncthreads();  // drains vmcnt (kt+1 loads) + protects buffer reuse
  }
}

// acc(node,h-out) = Gs @ WT^T, weights streamed from global (L2-hot)
__device__ __forceinline__ void gate_gemm(const f16* Gs, const f16* WT,
                                          int wm, int wn, int g, int r,
                                          f32x4 (&acc)[4][4]) {
#pragma unroll
  for (int kk = 0; kk < 4; ++kk) {
    f16x8 wf[4], af[4];
#pragma unroll
    for (int j = 0; j < 4; ++j)
      wf[j] = *(const f16x8*)&WT[(size_t)(wn + j * 16 + r) * 128 + kk * 32 + g * 8];
#pragma unroll
    for (int i = 0; i < 4; ++i) af[i] = frag128(Gs, wm + i * 16 + r, (kk << 2) | g);
#pragma unroll
    for (int i = 0; i < 4; ++i)
#pragma unroll
      for (int j = 0; j < 4; ++j)
        acc[i][j] = MFMA(af[i], wf[j], acc[i][j]);
  }
}

__global__ __launch_bounds__(256, 1)
void persist(const f16* __restrict__ A16, const f16* __restrict__ AX,
             const f16* __restrict__ WzT, const f16* __restrict__ WrT,
             const f16* __restrict__ WhT,
             const float* __restrict__ Wzf, const float* __restrict__ bz,
             const float* __restrict__ Wrf, const float* __restrict__ br,
             const float* __restrict__ Whf, const float* __restrict__ bh,
             const float* __restrict__ Whead, const float* __restrict__ bhead,
             f16* __restrict__ Ha, f16* __restrict__ Hb,
             f16* __restrict__ RHT, unsigned* __restrict__ bar,
             float* __restrict__ out) {
  __shared__ __align__(16) char sm[70656];
  f16* Gs = (f16*)sm;              // 32KB: staging ping-pong, then G tile
  f16* Ct = (f16*)(sm + 32768);    // 32KB: transpose scratch / head weights
  f16* AXs = (f16*)(sm + 65536);   // 512B
  float* wp = (float*)(sm + 66048);  // 9*128 f32

  const int tid = threadIdx.x;
  const int lane = tid & 63;
  const int g = lane >> 4, r = lane & 15;
  const int wid = tid >> 6;
  const int wm = (wid >> 1) * 64, wn = (wid & 1) * 64;
  const int b = blockIdx.x >> 2, nc = blockIdx.x & 3;
  const int m0 = nc * 128;

  // epilogue scalar weights (constant over t)
  for (int idx = tid; idx < 1152; idx += 256) {
    int row = idx >> 7, j = idx & 127;
    float v;
    if (row == 0) v = Wzf[j];
    else if (row == 1) v = Wzf[128 + j];
    else if (row == 2) v = bz[j];
    else if (row == 3) v = Wrf[j];
    else if (row == 4) v = Wrf[128 + j];
    else if (row == 5) v = br[j];
    else if (row == 6) v = Whf[j];
    else if (row == 7) v = Whf[128 + j];
    else v = bh[j];
    wp[idx] = v;
  }

  // per-thread staging offsets for [128][32] chunks (ld=512)
  const int lin0 = tid * 16, lin1 = 4096 + tid * 16;
  const int rA0 = lin0 >> 6, rA1 = lin1 >> 6;
  const int c0 = ((lin0 >> 4) & 3) ^ (rA0 & 3);
  const int c1 = ((lin1 >> 4) & 3) ^ (rA1 & 3);
  const size_t offA0 = (size_t)rA0 * 512 + c0 * 8;
  const size_t offA1 = (size_t)rA1 * 512 + c1 * 8;

  const f16* Atile = A16 + (size_t)m0 * 512;
  f16* hc = Ha + (size_t)b * 65536;
  f16* hn = Hb + (size_t)b * 65536;
  f16* rh = RHT + (size_t)b * 65536;
  unsigned* mybar = bar + b * 16;
  unsigned nbar = 0;
  f16x8 zreg[8], hvreg[8];

  for (int t = 0; t < 24; ++t) {
    if (tid < 128) {
      int cf = b * 48 + t * 2;
      const f16* p = AX + (size_t)(cf >> 7) * 65536 + (size_t)(m0 + tid) * 128 + (cf & 127);
      AXs[2 * tid] = p[0];
      AXs[2 * tid + 1] = p[1];
    }
    // ---- phase 1A: G = A @ h ----
    f32x4 acc[4][4] = {};
    phase1(Atile, hc, sm, wid, wm, wn, g, r, offA0, offA1, acc);
#pragma unroll
    for (int i = 0; i < 4; ++i)
#pragma unroll
      for (int j = 0; j < 4; ++j)
#pragma unroll
        for (int q = 0; q < 4; ++q)
          *elem128(Gs, wm + i * 16 + g * 4 + q, wn + j * 16 + r) = (f16)acc[i][j][q];
    __syncthreads();
    // ---- z gate (stays in registers) ----
    {
      f32x4 az[4][4] = {};
      gate_gemm(Gs, WzT, wm, wn, g, r, az);
#pragma unroll
      for (int i = 0; i < 4; ++i)
#pragma unroll
        for (int j = 0; j < 4; ++j)
#pragma unroll
          for (int q = 0; q < 4; ++q)
            *elem128(Ct, wn + j * 16 + r, wm + i * 16 + g * 4 + q) = (f16)az[i][j][q];
      __syncthreads();
#pragma unroll
      for (int p = 0; p < 8; ++p) {
        int hh = p * 16 + (tid >> 4), c = tid & 15, nl0 = c * 8;
        f16x8 cv = frag128(Ct, hh, c);
        float w0 = wp[hh], w1 = wp[128 + hh], bb = wp[256 + hh];
        f16x8 o;
#pragma unroll
        for (int e = 0; e < 8; ++e) {
          int nl = nl0 + e;
          float gx = (float)AXs[2 * nl] * w0 + (float)AXs[2 * nl + 1] * w1 + bb;
          o[e] = (f16)sigm((float)cv[e] + gx);
        }
        zreg[p] = o;
      }
      __syncthreads();
    }
    // ---- r gate -> rh = r*h (global, group-shared) ----
    {
      f32x4 ar[4][4] = {};
      gate_gemm(Gs, WrT, wm, wn, g, r, ar);
#pragma unroll
      for (int i = 0; i < 4; ++i)
#pragma unroll
        for (int j = 0; j < 4; ++j)
#pragma unroll
          for (int q = 0; q < 4; ++q)
            *elem128(Ct, wn + j * 16 + r, wm + i * 16 + g * 4 + q) = (f16)ar[i][j][q];
      __syncthreads();
#pragma unroll
      for (int p = 0; p < 8; ++p) {
        int hh = p * 16 + (tid >> 4), c = tid & 15, nl0 = c * 8;
        f16x8 cv = frag128(Ct, hh, c);
        f16x8 hv = *(const f16x8*)&hc[(size_t)hh * 512 + m0 + nl0];
        float w0 = wp[384 + hh], w1 = wp[512 + hh], bb = wp[640 + hh];
        f16x8 o;
#pragma unroll
        for (int e = 0; e < 8; ++e) {
          int nl = nl0 + e;
          float gx = (float)AXs[2 * nl] * w0 + (float)AXs[2 * nl + 1] * w1 + bb;
          float rv = sigm((float)cv[e] + gx);
          o[e] = (f16)(rv * (float)hv[e]);
        }
        hvreg[p] = hv;
        *(f16x8*)&rh[(size_t)hh * 512 + m0 + nl0] = o;
      }
    }
    group_sync(mybar, 4u * (++nbar));
    // ---- phase 1B: Gh = A @ (r*h) ----
    f32x4 acc2[4][4] = {};
    phase1(Atile, rh, sm, wid, wm, wn, g, r, offA0, offA1, acc2);
#pragma unroll
    for (int i = 0; i < 4; ++i)
#pragma unroll
      for (int j = 0; j < 4; ++j)
#pragma unroll
        for (int q = 0; q < 4; ++q)
          *elem128(Gs, wm + i * 16 + g * 4 + q, wn + j * 16 + r) = (f16)acc2[i][j][q];
    __syncthreads();
    // ---- h_tilde + update ----
    {
      f32x4 ah[4][4] = {};
      gate_gemm(Gs, WhT, wm, wn, g, r, ah);
#pragma unroll
      for (int i = 0; i < 4; ++i)
#pragma unroll
        for (int j = 0; j < 4; ++j)
#pragma unroll
          for (int q = 0; q < 4; ++q)
            *elem128(Ct, wn + j * 16 + r, wm + i * 16 + g * 4 + q) = (f16)ah[i][j][q];
      __syncthreads();
#pragma unroll
      for (int p = 0; p < 8; ++p) {
        int hh = p * 16 + (tid >> 4), c = tid & 15, nl0 = c * 8;
        f16x8 cv = frag128(Ct, hh, c);
        float w0 = wp[768 + hh], w1 = wp[896 + hh], bb = wp[1024 + hh];
        f16x8 o;
#pragma unroll
        for (int e = 0; e < 8; ++e) {
          int nl = nl0 + e;
          float gx = (float)AXs[2 * nl] * w0 + (float)AXs[2 * nl + 1] * w1 + bb;
          float ht = tanhfast((float)cv[e] + gx);
          float z = (float)zreg[p][e];
          o[e] = (f16)((1.f - z) * (float)hvreg[p][e] + z * ht);
        }
        if (t < 23) {
          *(f16x8*)&hn[(size_t)hh * 512 + m0 + nl0] = o;
        } else {
          *(f16x8*)((char*)Gs + hh * 256 + nl0 * 2) = o;  // final h, linear [h][node]
        }
      }
    }
    if (t < 23) {
      group_sync(mybar, 4u * (++nbar));
      f16* tmp = hc; hc = hn; hn = tmp;
    }
  }
  // ---- head: out[b, :, m0..m0+127] from final h in LDS ----
  __syncthreads();
  float* Ws = (float*)Ct;
  for (int idx = tid; idx < 1548; idx += 256)
    Ws[idx] = (idx < 1536) ? Whead[idx] : bhead[idx - 1536];
  __syncthreads();
  {
    int n = tid & 127, half = tid >> 7;
    float pa[12];
#pragma unroll
    for (int o = 0; o < 12; ++o) pa[o] = 0.f;
    const f16* Hfin = (const f16*)Gs;
    for (int h = half * 64; h < half * 64 + 64; ++h) {
      float v = (float)Hfin[h * 128 + n];
#pragma unroll
      for (int o = 0; o < 12; ++o) pa[o] += v * Ws[h * 12 + o];
    }
    float* P = (float*)(sm + 32768 + 8192);
#pragma unroll
    for (int o = 0; o < 12; ++o) P[(n * 2 + half) * 12 + o] = pa[o];
    __syncthreads();
    if (half == 0) {
#pragma unroll
      for (int o = 0; o < 12; ++o)
        out[(size_t)b * 6144 + o * 512 + m0 + n] = P[n * 24 + o] + P[n * 24 + 12 + o] + Ws[1536 + o];
    }
  }
}

// ---------- setup kernels (one-time) ----------
__device__ __forceinline__ void stage128x64(const f16* src, int row0, int ld, int k0,
                                            f16* lds, int tid) {
  int wid = tid >> 6;
#pragma unroll
  for (int q = 0; q < 4; ++q) {
    int lin = q * 4096 + tid * 16;
    int row = lin >> 7;
    int ch = (lin >> 4) & 7;
    int sch = ch ^ (row & 7);
    gload16(src + (size_t)(row0 + row) * ld + k0 + sch * 8,
            (char*)lds + q * 4096 + wid * 1024);
  }
}

__global__ __launch_bounds__(256, 2)
void gemm512(const f16* __restrict__ A, const f16* __restrict__ B,
             f16* __restrict__ C) {
  __shared__ __align__(16) char sm[34816];
  f16* As = (f16*)sm;
  f16* Bs = (f16*)(sm + 16384);
  const int tid = threadIdx.x;
  const int lane = tid & 63;
  const int g = lane >> 4, r = lane & 15;
  const int wid = tid >> 6;
  const int wm = (wid >> 1) * 64, wn = (wid & 1) * 64;
  const int m0 = blockIdx.y * 128;
  const int n0 = blockIdx.x * 128;
  f32x4 acc[4][4] = {};
  for (int kt = 0; kt < 8; ++kt) {
    stage128x64(A, m0, 512, kt * 64, As, tid);
    stage128x64(B, n0, 512, kt * 64, Bs, tid);
    __syncthreads();
#pragma unroll
    for (int kk = 0; kk < 2; ++kk) {
      f16x8 af[4], bf[4];
#pragma unroll
      for (int i = 0; i < 4; ++i) af[i] = frag64(As, wm + i * 16 + r, (kk << 2) | g);
#pragma unroll
      for (int j = 0; j < 4; ++j) bf[j] = frag64(Bs, wn + j * 16 + r, (kk << 2) | g);
#pragma unroll
      for (int i = 0; i < 4; ++i)
#pragma unroll
        for (int j = 0; j < 4; ++j)
          acc[i][j] = MFMA(af[i], bf[j], acc[i][j]);
    }
    __syncthreads();
  }
  f16* Ctl = (f16*)sm;
#pragma unroll
  for (int i = 0; i < 4; ++i)
#pragma unroll
    for (int j = 0; j < 4; ++j) {
      int col = wn + j * 16 + r;
#pragma unroll
      for (int q = 0; q < 4; ++q) {
        int row = wm + i * 16 + g * 4 + q;
        Ctl[row * 136 + col] = (f16)acc[i][j][q];
      }
    }
  __syncthreads();
  f16* Cb = C + (size_t)blockIdx.x * 65536;
#pragma unroll
  for (int p = 0; p < 8; ++p) {
    int row = p * 16 + (tid >> 4);
    int c0 = (tid & 15) * 8;
    f16x8 v = *(const f16x8*)&Ctl[row * 136 + c0];
    *(f16x8*)&Cb[(size_t)(m0 + row) * 128 + c0] = v;
  }
}

__global__ void m12k(const float* __restrict__ E, const float* __restrict__ W1,
                     const float* __restrict__ W2, float* __restrict__ M1,
                     float* __restrict__ M2) {
  int idx = blockIdx.x * 256 + threadIdx.x;
  if (idx >= 16384) return;
  int which = idx >> 13;
  int rem = idx & 8191;
  int n = rem >> 4, j = rem & 15;
  const float* W = which ? W2 : W1;
  float s = 0.f;
#pragma unroll
  for (int k = 0; k < 16; ++k) s += E[n * 16 + k] * W[k * 16 + j];
  (which ? M2 : M1)[n * 16 + j] = s;
}

__global__ __launch_bounds__(256)
void softA(const float* __restrict__ M1, const float* __restrict__ M2,
           f16* __restrict__ A16) {
  __shared__ float M2s[8192];
  __shared__ float m1s[16];
  __shared__ float red[8];
  int i = blockIdx.x, tid = threadIdx.x;
  for (int q = tid; q < 8192; q += 256) M2s[q] = M2[q];
  if (tid < 16) m1s[tid] = M1[i * 16 + tid];
  __syncthreads();
  float s0 = 0.f, s1 = 0.f;
#pragma unroll
  for (int k = 0; k < 16; ++k) {
    float a = m1s[k];
    s0 += a * M2s[tid * 16 + k];
    s1 += a * M2s[(tid + 256) * 16 + k];
  }
  s0 = fmaxf(s0, 0.f);
  s1 = fmaxf(s1, 0.f);
  float m = fmaxf(s0, s1);
  for (int o = 32; o > 0; o >>= 1) m = fmaxf(m, __shfl_xor(m, o));
  if ((tid & 63) == 0) red[tid >> 6] = m;
  __syncthreads();
  m = fmaxf(fmaxf(red[0], red[1]), fmaxf(red[2], red[3]));
  float e0 = expf(s0 - m), e1 = expf(s1 - m);
  float ss = e0 + e1;
  for (int o = 32; o > 0; o >>= 1) ss += __shfl_xor(ss, o);
  __syncthreads();
  if ((tid & 63) == 0) red[4 + (tid >> 6)] = ss;
  __syncthreads();
  ss = (red[4] + red[5]) + (red[6] + red[7]);
  float inv = 1.f / ss;
  A16[(size_t)i * 512 + tid] = (f16)(e0 * inv);
  A16[(size_t)i * 512 + tid + 256] = (f16)(e1 * inv);
}

__global__ void wTk(const float* __restrict__ Wz, const float* __restrict__ Wr,
                    const float* __restrict__ Wh, f16* __restrict__ WzT,
                    f16* __restrict__ WrT, f16* __restrict__ WhT) {
  int idx = blockIdx.x * 256 + threadIdx.x;
  if (idx >= 49152) return;
  int w = idx / 16384;
  int rem = idx & 16383;
  int hp = rem >> 7, k = rem & 127;
  const float* S = (w == 0) ? Wz : ((w == 1) ? Wr : Wh);
  f16* D = (w == 0) ? WzT : ((w == 1) ? WrT : WhT);
  D[hp * 128 + k] = (f16)S[(2 + k) * 128 + hp];
}

__global__ void xTk(const float* __restrict__ X, f16* __restrict__ XTT) {
  int idx = blockIdx.x * 256 + threadIdx.x;
  if (idx >= 786432) return;
  int m = idx & 511;
  int bt = idx >> 9;
  float x0 = X[(size_t)idx * 2];
  float x1 = X[(size_t)idx * 2 + 1];
  XTT[(size_t)(bt * 2 + 0) * 512 + m] = (f16)x0;
  XTT[(size_t)(bt * 2 + 1) * 512 + m] = (f16)x1;
}

extern "C" void kernel_launch(void* const* d_in, const int* in_sizes, int n_in,
                              void* d_out, int out_size, void* d_ws, size_t ws_size,
                              hipStream_t stream) {
  (void)in_sizes; (void)n_in; (void)out_size; (void)ws_size;
  const float* X = (const float*)d_in[0];
  const float* E = (const float*)d_in[1];
  const float* W1 = (const float*)d_in[2];
  const float* W2 = (const float*)d_in[3];
  const float* Wz = (const float*)d_in[4];
  const float* bz = (const float*)d_in[5];
  const float* Wr = (const float*)d_in[6];
  const float* br = (const float*)d_in[7];
  const float* Wh = (const float*)d_in[8];
  const float* bh = (const float*)d_in[9];
  const float* Whead = (const float*)d_in[10];
  const float* bhead = (const float*)d_in[11];
  float* out = (float*)d_out;
  char* ws = (char*)d_ws;

  f16* A16 = (f16*)(ws + 0);           // 512x512
  f16* XTT = (f16*)(ws + 524288);      // 3072x512
  f16* AX  = (f16*)(ws + 3670016);     // [24 tiles][512][128]
  f16* Ha  = (f16*)(ws + 6815744);     // [64][128][512]
  f16* Hb  = (f16*)(ws + 15204352);
  f16* RHT = (f16*)(ws + 23592960);    // [64][128][512]
  f16* WzT = (f16*)(ws + 31981568);    // 128x128 f16
  f16* WrT = (f16*)(ws + 32014336);
  f16* WhT = (f16*)(ws + 32047104);
  float* M1 = (float*)(ws + 32079872);
  float* M2 = (float*)(ws + 32112640);
  unsigned* bar = (unsigned*)(ws + 32145408);  // 64 groups x 16 u32

  hipMemsetAsync(Ha, 0, 8388608, stream);
  hipMemsetAsync(bar, 0, 4096, stream);
  m12k<<<64, 256, 0, stream>>>(E, W1, W2, M1, M2);
  softA<<<512, 256, 0, stream>>>(M1, M2, A16);
  wTk<<<192, 256, 0, stream>>>(Wz, Wr, Wh, WzT, WrT, WhT);
  xTk<<<3072, 256, 0, stream>>>(X, XTT);
  gemm512<<<dim3(24, 4), 256, 0, stream>>>(A16, XTT, AX);
  persist<<<256, 256, 0, stream>>>(A16, AX, WzT, WrT, WhT, Wz, bz, Wr, br, Wh, bh,
                                   Whead, bhead, Ha, Hb, RHT, bar, out);
}

// Round 4
// 842.137 us; speedup vs baseline: 1.8781x; 1.8781x over previous
//
#include <hip/hip_runtime.h>

typedef _Float16 f16;
typedef _Float16 f16x8 __attribute__((ext_vector_type(8)));
typedef float f32x4 __attribute__((ext_vector_type(4)));

typedef const __attribute__((address_space(1))) void GV;
typedef __attribute__((address_space(3))) void LV;

__device__ __forceinline__ void gload16(const void* g, void* l) {
  __builtin_amdgcn_global_load_lds((GV*)g, (LV*)l, 16, 0, 0);
}

#define WAIT_VM0() asm volatile("s_waitcnt vmcnt(0)" ::: "memory")

// coherent-point (Infinity Cache) access: bypass L1+L2 on both sides
__device__ __forceinline__ f16x8 ntload16(const f16* p) {
  f16x8 v;
  asm volatile("global_load_dwordx4 %0, %1, off sc0 sc1" : "=v"(v) : "v"(p));
  return v;
}
__device__ __forceinline__ void ntstore16(f16* p, f16x8 v) {
  asm volatile("global_store_dwordx4 %0, %1, off sc0 sc1" :: "v"(p), "v"(v) : "memory");
}
__device__ __forceinline__ unsigned ntload_u32(const unsigned* p) {
  unsigned v;
  asm volatile("global_load_dword %0, %1, off sc0 sc1\n\ts_waitcnt vmcnt(0)"
               : "=v"(v) : "v"(p) : "memory");
  return v;
}

// ---- fragment helpers ----
// [128][64] f16 tile (16KB), row stride 128B, swizzle ch^=row&7 (2-way free)
__device__ __forceinline__ f16x8 frag64(const f16* T, int row, int chunk) {
  int ch = chunk ^ (row & 7);
  return *(const f16x8*)((const char*)T + row * 128 + ch * 16);
}
// [128][128] f16 tile (32KB), row stride 256B, full-XOR swizzle
__device__ __forceinline__ f16x8 frag128(const f16* T, int row, int chunk) {
  int ch = chunk ^ (row & 15);
  return *(const f16x8*)((const char*)T + row * 256 + ch * 16);
}
__device__ __forceinline__ f16* elem128(f16* T, int row, int col) {
  return (f16*)((char*)T + row * 256 + (((col >> 3) ^ (row & 15)) << 4) + (col & 7) * 2);
}

#define MFMA(a, b, c) __builtin_amdgcn_mfma_f32_16x16x32_f16(a, b, c, 0, 0, 0)

__device__ __forceinline__ float sigm(float v) { return 1.f / (1.f + __expf(-v)); }
__device__ __forceinline__ float tanhfast(float v) { return 1.f - 2.f / (1.f + __expf(2.f * v)); }

// 4-block group barrier: relaxed device-scope atomic + sc0sc1 spin.
// NO cache maintenance -> L2 keeps A16/weights hot. Data exchange is via
// ntstore/ntload which meet at the die-level Infinity Cache.
__device__ __forceinline__ void group_sync(unsigned* bar, unsigned target) {
  __syncthreads();  // drains vmcnt(0): all nt-stores at coherent point
  if (threadIdx.x == 0) {
    atomicAdd(bar, 1u);
    int guard = 0;
    while (ntload_u32(bar) < target) {
      __builtin_amdgcn_s_sleep(2);
      if (++guard > 4000000) break;  // fail loud, not hang
    }
  }
  __syncthreads();
}

// stage a [128][64] A-chunk (cached path, global_load_lds)
__device__ __forceinline__ void stageA4(const f16* src, char* ldsb, int tid,
                                        const size_t (&offs)[4]) {
  int wb = (tid >> 6) * 1024;
  gload16(src + offs[0], ldsb + wb);
  gload16(src + offs[1], ldsb + 4096 + wb);
  gload16(src + offs[2], ldsb + 8192 + wb);
  gload16(src + offs[3], ldsb + 12288 + wb);
}

__device__ __forceinline__ void p1_compute(const f16* Ta, const f16* Tb,
                                           int wm, int wn, int g, int r,
                                           f32x4 (&acc)[4][4]) {
#pragma unroll
  for (int kk = 0; kk < 2; ++kk) {
    f16x8 af[4], bf[4];
#pragma unroll
    for (int i = 0; i < 4; ++i) af[i] = frag64(Ta, wm + i * 16 + r, (kk << 2) | g);
#pragma unroll
    for (int j = 0; j < 4; ++j) bf[j] = frag64(Tb, wn + j * 16 + r, (kk << 2) | g);
#pragma unroll
    for (int i = 0; i < 4; ++i)
#pragma unroll
      for (int j = 0; j < 4; ++j)
        acc[i][j] = MFMA(af[i], bf[j], acc[i][j]);
  }
}

// acc[node 128][512-K] = A_tile @ B ; A cached (LDS-DMA), B via coherent
// reg-staged loads (sc0sc1) -> vmcnt(0) -> ds_write_b128. Double-buffered.
__device__ __forceinline__ void phase1(const f16* Atile, const f16* Bsrc,
                                       char* smbase, int tid, int wm, int wn,
                                       int g, int r, const size_t (&offs)[4],
                                       f32x4 (&acc)[4][4]) {
  stageA4(Atile, smbase, tid, offs);
  f16x8 c0 = ntload16(Bsrc + offs[0]);
  f16x8 c1 = ntload16(Bsrc + offs[1]);
  f16x8 c2 = ntload16(Bsrc + offs[2]);
  f16x8 c3 = ntload16(Bsrc + offs[3]);
  WAIT_VM0();
  {
    char* bb = smbase + 16384;
    *(f16x8*)(bb + tid * 16) = c0;
    *(f16x8*)(bb + 4096 + tid * 16) = c1;
    *(f16x8*)(bb + 8192 + tid * 16) = c2;
    *(f16x8*)(bb + 12288 + tid * 16) = c3;
  }
  __syncthreads();
#pragma unroll 1
  for (int kt = 0; kt < 8; ++kt) {
    int sel = kt & 1;
    char* cur = smbase + sel * 32768;
    char* nxt = smbase + (sel ^ 1) * 32768;
    if (kt < 7) {
      stageA4(Atile + (kt + 1) * 64, nxt, tid, offs);
      const f16* bp = Bsrc + (kt + 1) * 64;
      c0 = ntload16(bp + offs[0]);
      c1 = ntload16(bp + offs[1]);
      c2 = ntload16(bp + offs[2]);
      c3 = ntload16(bp + offs[3]);
    }
    p1_compute((const f16*)cur, (const f16*)(cur + 16384), wm, wn, g, r, acc);
    if (kt < 7) {
      WAIT_VM0();
      char* nb = nxt + 16384;
      *(f16x8*)(nb + tid * 16) = c0;
      *(f16x8*)(nb + 4096 + tid * 16) = c1;
      *(f16x8*)(nb + 8192 + tid * 16) = c2;
      *(f16x8*)(nb + 12288 + tid * 16) = c3;
    }
    __syncthreads();
  }
}

// acc(node,h-out) = Gs @ WT^T, weights streamed from global (L2-hot)
__device__ __forceinline__ void gate_gemm(const f16* Gs, const f16* WT,
                                          int wm, int wn, int g, int r,
                                          f32x4 (&acc)[4][4]) {
#pragma unroll
  for (int kk = 0; kk < 4; ++kk) {
    f16x8 wf[4], af[4];
#pragma unroll
    for (int j = 0; j < 4; ++j)
      wf[j] = *(const f16x8*)&WT[(size_t)(wn + j * 16 + r) * 128 + kk * 32 + g * 8];
#pragma unroll
    for (int i = 0; i < 4; ++i) af[i] = frag128(Gs, wm + i * 16 + r, (kk << 2) | g);
#pragma unroll
    for (int i = 0; i < 4; ++i)
#pragma unroll
      for (int j = 0; j < 4; ++j)
        acc[i][j] = MFMA(af[i], wf[j], acc[i][j]);
  }
}

__global__ __launch_bounds__(256, 1)
void persist(const f16* __restrict__ A16, const f16* __restrict__ AX,
             const f16* __restrict__ WzT, const f16* __restrict__ WrT,
             const f16* __restrict__ WhT,
             const float* __restrict__ Wzf, const float* __restrict__ bz,
             const float* __restrict__ Wrf, const float* __restrict__ br,
             const float* __restrict__ Whf, const float* __restrict__ bh,
             const float* __restrict__ Whead, const float* __restrict__ bhead,
             f16* __restrict__ Ha, f16* __restrict__ Hb,
             f16* __restrict__ RHT, unsigned* __restrict__ bar,
             float* __restrict__ out) {
  __shared__ __align__(16) char sm[136192];
  // 0..65536: staging double buffer (2 x [A 16K | B 16K])
  f16* Gs = (f16*)(sm + 65536);      // 32KB G tile
  f16* Ct = (f16*)(sm + 98304);      // 32KB transpose scratch / head W
  f16* AXs = (f16*)(sm + 131072);    // 512B
  float* wp = (float*)(sm + 131584); // 9*128 f32

  const int tid = threadIdx.x;
  const int lane = tid & 63;
  const int g = lane >> 4, r = lane & 15;
  const int wid = tid >> 6;
  const int wm = (wid >> 1) * 64, wn = (wid & 1) * 64;
  const int b = blockIdx.x >> 2, nc = blockIdx.x & 3;
  const int m0 = nc * 128;

  for (int idx = tid; idx < 1152; idx += 256) {
    int row = idx >> 7, j = idx & 127;
    float v;
    if (row == 0) v = Wzf[j];
    else if (row == 1) v = Wzf[128 + j];
    else if (row == 2) v = bz[j];
    else if (row == 3) v = Wrf[j];
    else if (row == 4) v = Wrf[128 + j];
    else if (row == 5) v = br[j];
    else if (row == 6) v = Whf[j];
    else if (row == 7) v = Whf[128 + j];
    else v = bh[j];
    wp[idx] = v;
  }

  // swizzled per-thread offsets into a [128][64] chunk of an ld=512 source
  size_t offs[4];
#pragma unroll
  for (int q = 0; q < 4; ++q) {
    int lin = q * 4096 + tid * 16;
    int row = lin >> 7;
    int ch = ((lin >> 4) & 7) ^ (row & 7);
    offs[q] = (size_t)row * 512 + ch * 8;
  }

  const f16* Atile = A16 + (size_t)m0 * 512;
  f16* hc = Ha + (size_t)b * 65536;
  f16* hn = Hb + (size_t)b * 65536;
  f16* rh = RHT + (size_t)b * 65536;
  unsigned* mybar = bar + b * 64;
  unsigned nbar = 0;
  f16x8 zreg[8];
  f16x8 hvreg[8] = {};  // own h tile [hh][node], carried across steps (h0=0)

  for (int t = 0; t < 24; ++t) {
    if (tid < 128) {
      int cf = b * 48 + t * 2;
      const f16* p = AX + (size_t)(cf >> 7) * 65536 + (size_t)(m0 + tid) * 128 + (cf & 127);
      AXs[2 * tid] = p[0];
      AXs[2 * tid + 1] = p[1];
    }
    // ---- phase 1A: G = A @ h ----
    f32x4 acc[4][4] = {};
    phase1(Atile, hc, sm, tid, wm, wn, g, r, offs, acc);
#pragma unroll
    for (int i = 0; i < 4; ++i)
#pragma unroll
      for (int j = 0; j < 4; ++j)
#pragma unroll
        for (int q = 0; q < 4; ++q)
          *elem128(Gs, wm + i * 16 + g * 4 + q, wn + j * 16 + r) = (f16)acc[i][j][q];
    __syncthreads();
    // ---- z gate (stays in registers) ----
    {
      f32x4 az[4][4] = {};
      gate_gemm(Gs, WzT, wm, wn, g, r, az);
#pragma unroll
      for (int i = 0; i < 4; ++i)
#pragma unroll
        for (int j = 0; j < 4; ++j)
#pragma unroll
          for (int q = 0; q < 4; ++q)
            *elem128(Ct, wn + j * 16 + r, wm + i * 16 + g * 4 + q) = (f16)az[i][j][q];
      __syncthreads();
#pragma unroll
      for (int p = 0; p < 8; ++p) {
        int hh = p * 16 + (tid >> 4), c = tid & 15, nl0 = c * 8;
        f16x8 cv = frag128(Ct, hh, c);
        float w0 = wp[hh], w1 = wp[128 + hh], bb = wp[256 + hh];
        f16x8 o;
#pragma unroll
        for (int e = 0; e < 8; ++e) {
          int nl = nl0 + e;
          float gx = (float)AXs[2 * nl] * w0 + (float)AXs[2 * nl + 1] * w1 + bb;
          o[e] = (f16)sigm((float)cv[e] + gx);
        }
        zreg[p] = o;
      }
      __syncthreads();
    }
    // ---- r gate -> rh = r*h (coherent store, group-shared) ----
    {
      f32x4 ar[4][4] = {};
      gate_gemm(Gs, WrT, wm, wn, g, r, ar);
#pragma unroll
      for (int i = 0; i < 4; ++i)
#pragma unroll
        for (int j = 0; j < 4; ++j)
#pragma unroll
          for (int q = 0; q < 4; ++q)
            *elem128(Ct, wn + j * 16 + r, wm + i * 16 + g * 4 + q) = (f16)ar[i][j][q];
      __syncthreads();
#pragma unroll
      for (int p = 0; p < 8; ++p) {
        int hh = p * 16 + (tid >> 4), c = tid & 15, nl0 = c * 8;
        f16x8 cv = frag128(Ct, hh, c);
        f16x8 hv = hvreg[p];
        float w0 = wp[384 + hh], w1 = wp[512 + hh], bb = wp[640 + hh];
        f16x8 o;
#pragma unroll
        for (int e = 0; e < 8; ++e) {
          int nl = nl0 + e;
          float gx = (float)AXs[2 * nl] * w0 + (float)AXs[2 * nl + 1] * w1 + bb;
          float rv = sigm((float)cv[e] + gx);
          o[e] = (f16)(rv * (float)hv[e]);
        }
        ntstore16(&rh[(size_t)hh * 512 + m0 + nl0], o);
      }
    }
    group_sync(mybar, 4u * (++nbar));
    // ---- phase 1B: Gh = A @ (r*h) ----
    f32x4 acc2[4][4] = {};
    phase1(Atile, rh, sm, tid, wm, wn, g, r, offs, acc2);
#pragma unroll
    for (int i = 0; i < 4; ++i)
#pragma unroll
      for (int j = 0; j < 4; ++j)
#pragma unroll
        for (int q = 0; q < 4; ++q)
          *elem128(Gs, wm + i * 16 + g * 4 + q, wn + j * 16 + r) = (f16)acc2[i][j][q];
    __syncthreads();
    // ---- h_tilde + update ----
    {
      f32x4 ah[4][4] = {};
      gate_gemm(Gs, WhT, wm, wn, g, r, ah);
#pragma unroll
      for (int i = 0; i < 4; ++i)
#pragma unroll
        for (int j = 0; j < 4; ++j)
#pragma unroll
          for (int q = 0; q < 4; ++q)
            *elem128(Ct, wn + j * 16 + r, wm + i * 16 + g * 4 + q) = (f16)ah[i][j][q];
      __syncthreads();
#pragma unroll
      for (int p = 0; p < 8; ++p) {
        int hh = p * 16 + (tid >> 4), c = tid & 15, nl0 = c * 8;
        f16x8 cv = frag128(Ct, hh, c);
        float w0 = wp[768 + hh], w1 = wp[896 + hh], bb = wp[1024 + hh];
        f16x8 hv = hvreg[p], zv = zreg[p];
        f16x8 o;
#pragma unroll
        for (int e = 0; e < 8; ++e) {
          int nl = nl0 + e;
          float gx = (float)AXs[2 * nl] * w0 + (float)AXs[2 * nl + 1] * w1 + bb;
          float ht = tanhfast((float)cv[e] + gx);
          float z = (float)zv[e];
          o[e] = (f16)((1.f - z) * (float)hv[e] + z * ht);
        }
        hvreg[p] = o;
        if (t < 23) {
          ntstore16(&hn[(size_t)hh * 512 + m0 + nl0], o);
        } else {
          *(f16x8*)((char*)Gs + hh * 256 + nl0 * 2) = o;  // final h, linear [h][node]
        }
      }
    }
    if (t < 23) {
      group_sync(mybar, 4u * (++nbar));
      f16* tmp = hc; hc = hn; hn = tmp;
    }
  }
  // ---- head: out[b, :, m0..m0+127] from final h in LDS ----
  __syncthreads();
  float* Ws = (float*)Ct;
  for (int idx = tid; idx < 1548; idx += 256)
    Ws[idx] = (idx < 1536) ? Whead[idx] : bhead[idx - 1536];
  __syncthreads();
  {
    int n = tid & 127, half = tid >> 7;
    float pa[12];
#pragma unroll
    for (int o = 0; o < 12; ++o) pa[o] = 0.f;
    const f16* Hfin = (const f16*)Gs;
    for (int h = half * 64; h < half * 64 + 64; ++h) {
      float v = (float)Hfin[h * 128 + n];
#pragma unroll
      for (int o = 0; o < 12; ++o) pa[o] += v * Ws[h * 12 + o];
    }
    float* P = (float*)(sm + 40960);
#pragma unroll
    for (int o = 0; o < 12; ++o) P[(n * 2 + half) * 12 + o] = pa[o];
    __syncthreads();
    if (half == 0) {
#pragma unroll
      for (int o = 0; o < 12; ++o)
        out[(size_t)b * 6144 + o * 512 + m0 + n] = P[n * 24 + o] + P[n * 24 + 12 + o] + Ws[1536 + o];
    }
  }
}

// ---------- setup kernels (one-time) ----------
__device__ __forceinline__ void stage128x64(const f16* src, int row0, int ld, int k0,
                                            f16* lds, int tid) {
  int wid = tid >> 6;
#pragma unroll
  for (int q = 0; q < 4; ++q) {
    int lin = q * 4096 + tid * 16;
    int row = lin >> 7;
    int ch = (lin >> 4) & 7;
    int sch = ch ^ (row & 7);
    gload16(src + (size_t)(row0 + row) * ld + k0 + sch * 8,
            (char*)lds + q * 4096 + wid * 1024);
  }
}

__global__ __launch_bounds__(256, 2)
void gemm512(const f16* __restrict__ A, const f16* __restrict__ B,
             f16* __restrict__ C) {
  __shared__ __align__(16) char sm[34816];
  f16* As = (f16*)sm;
  f16* Bs = (f16*)(sm + 16384);
  const int tid = threadIdx.x;
  const int lane = tid & 63;
  const int g = lane >> 4, r = lane & 15;
  const int wid = tid >> 6;
  const int wm = (wid >> 1) * 64, wn = (wid & 1) * 64;
  const int m0 = blockIdx.y * 128;
  const int n0 = blockIdx.x * 128;
  f32x4 acc[4][4] = {};
  for (int kt = 0; kt < 8; ++kt) {
    stage128x64(A, m0, 512, kt * 64, As, tid);
    stage128x64(B, n0, 512, kt * 64, Bs, tid);
    __syncthreads();
#pragma unroll
    for (int kk = 0; kk < 2; ++kk) {
      f16x8 af[4], bf[4];
#pragma unroll
      for (int i = 0; i < 4; ++i) af[i] = frag64(As, wm + i * 16 + r, (kk << 2) | g);
#pragma unroll
      for (int j = 0; j < 4; ++j) bf[j] = frag64(Bs, wn + j * 16 + r, (kk << 2) | g);
#pragma unroll
      for (int i = 0; i < 4; ++i)
#pragma unroll
        for (int j = 0; j < 4; ++j)
          acc[i][j] = MFMA(af[i], bf[j], acc[i][j]);
    }
    __syncthreads();
  }
  f16* Ctl = (f16*)sm;
#pragma unroll
  for (int i = 0; i < 4; ++i)
#pragma unroll
    for (int j = 0; j < 4; ++j) {
      int col = wn + j * 16 + r;
#pragma unroll
      for (int q = 0; q < 4; ++q) {
        int row = wm + i * 16 + g * 4 + q;
        Ctl[row * 136 + col] = (f16)acc[i][j][q];
      }
    }
  __syncthreads();
  f16* Cb = C + (size_t)blockIdx.x * 65536;
#pragma unroll
  for (int p = 0; p < 8; ++p) {
    int row = p * 16 + (tid >> 4);
    int c0 = (tid & 15) * 8;
    f16x8 v = *(const f16x8*)&Ctl[row * 136 + c0];
    *(f16x8*)&Cb[(size_t)(m0 + row) * 128 + c0] = v;
  }
}

__global__ void m12k(const float* __restrict__ E, const float* __restrict__ W1,
                     const float* __restrict__ W2, float* __restrict__ M1,
                     float* __restrict__ M2) {
  int idx = blockIdx.x * 256 + threadIdx.x;
  if (idx >= 16384) return;
  int which = idx >> 13;
  int rem = idx & 8191;
  int n = rem >> 4, j = rem & 15;
  const float* W = which ? W2 : W1;
  float s = 0.f;
#pragma unroll
  for (int k = 0; k < 16; ++k) s += E[n * 16 + k] * W[k * 16 + j];
  (which ? M2 : M1)[n * 16 + j] = s;
}

__global__ __launch_bounds__(256)
void softA(const float* __restrict__ M1, const float* __restrict__ M2,
           f16* __restrict__ A16) {
  __shared__ float M2s[8192];
  __shared__ float m1s[16];
  __shared__ float red[8];
  int i = blockIdx.x, tid = threadIdx.x;
  for (int q = tid; q < 8192; q += 256) M2s[q] = M2[q];
  if (tid < 16) m1s[tid] = M1[i * 16 + tid];
  __syncthreads();
  float s0 = 0.f, s1 = 0.f;
#pragma unroll
  for (int k = 0; k < 16; ++k) {
    float a = m1s[k];
    s0 += a * M2s[tid * 16 + k];
    s1 += a * M2s[(tid + 256) * 16 + k];
  }
  s0 = fmaxf(s0, 0.f);
  s1 = fmaxf(s1, 0.f);
  float m = fmaxf(s0, s1);
  for (int o = 32; o > 0; o >>= 1) m = fmaxf(m, __shfl_xor(m, o));
  if ((tid & 63) == 0) red[tid >> 6] = m;
  __syncthreads();
  m = fmaxf(fmaxf(red[0], red[1]), fmaxf(red[2], red[3]));
  float e0 = expf(s0 - m), e1 = expf(s1 - m);
  float ss = e0 + e1;
  for (int o = 32; o > 0; o >>= 1) ss += __shfl_xor(ss, o);
  __syncthreads();
  if ((tid & 63) == 0) red[4 + (tid >> 6)] = ss;
  __syncthreads();
  ss = (red[4] + red[5]) + (red[6] + red[7]);
  float inv = 1.f / ss;
  A16[(size_t)i * 512 + tid] = (f16)(e0 * inv);
  A16[(size_t)i * 512 + tid + 256] = (f16)(e1 * inv);
}

__global__ void wTk(const float* __restrict__ Wz, const float* __restrict__ Wr,
                    const float* __restrict__ Wh, f16* __restrict__ WzT,
                    f16* __restrict__ WrT, f16* __restrict__ WhT) {
  int idx = blockIdx.x * 256 + threadIdx.x;
  if (idx >= 49152) return;
  int w = idx / 16384;
  int rem = idx & 16383;
  int hp = rem >> 7, k = rem & 127;
  const float* S = (w == 0) ? Wz : ((w == 1) ? Wr : Wh);
  f16* D = (w == 0) ? WzT : ((w == 1) ? WrT : WhT);
  D[hp * 128 + k] = (f16)S[(2 + k) * 128 + hp];
}

__global__ void xTk(const float* __restrict__ X, f16* __restrict__ XTT) {
  int idx = blockIdx.x * 256 + threadIdx.x;
  if (idx >= 786432) return;
  int m = idx & 511;
  int bt = idx >> 9;
  float x0 = X[(size_t)idx * 2];
  float x1 = X[(size_t)idx * 2 + 1];
  XTT[(size_t)(bt * 2 + 0) * 512 + m] = (f16)x0;
  XTT[(size_t)(bt * 2 + 1) * 512 + m] = (f16)x1;
}

extern "C" void kernel_launch(void* const* d_in, const int* in_sizes, int n_in,
                              void* d_out, int out_size, void* d_ws, size_t ws_size,
                              hipStream_t stream) {
  (void)in_sizes; (void)n_in; (void)out_size; (void)ws_size;
  const float* X = (const float*)d_in[0];
  const float* E = (const float*)d_in[1];
  const float* W1 = (const float*)d_in[2];
  const float* W2 = (const float*)d_in[3];
  const float* Wz = (const float*)d_in[4];
  const float* bz = (const float*)d_in[5];
  const float* Wr = (const float*)d_in[6];
  const float* br = (const float*)d_in[7];
  const float* Wh = (const float*)d_in[8];
  const float* bh = (const float*)d_in[9];
  const float* Whead = (const float*)d_in[10];
  const float* bhead = (const float*)d_in[11];
  float* out = (float*)d_out;
  char* ws = (char*)d_ws;

  f16* A16 = (f16*)(ws + 0);           // 512x512
  f16* XTT = (f16*)(ws + 524288);      // 3072x512
  f16* AX  = (f16*)(ws + 3670016);     // [24 tiles][512][128]
  f16* Ha  = (f16*)(ws + 6815744);     // [64][128][512]
  f16* Hb  = (f16*)(ws + 15204352);
  f16* RHT = (f16*)(ws + 23592960);    // [64][128][512]
  f16* WzT = (f16*)(ws + 31981568);    // 128x128 f16
  f16* WrT = (f16*)(ws + 32014336);
  f16* WhT = (f16*)(ws + 32047104);
  float* M1 = (float*)(ws + 32079872);
  float* M2 = (float*)(ws + 32112640);
  unsigned* bar = (unsigned*)(ws + 32145408);  // 64 groups x 256B

  hipMemsetAsync(Ha, 0, 8388608, stream);
  hipMemsetAsync(bar, 0, 16384, stream);
  m12k<<<64, 256, 0, stream>>>(E, W1, W2, M1, M2);
  softA<<<512, 256, 0, stream>>>(M1, M2, A16);
  wTk<<<192, 256, 0, stream>>>(Wz, Wr, Wh, WzT, WrT, WhT);
  xTk<<<3072, 256, 0, stream>>>(X, XTT);
  gemm512<<<dim3(24, 4), 256, 0, stream>>>(A16, XTT, AX);
  persist<<<256, 256, 0, stream>>>(A16, AX, WzT, WrT, WhT, Wz, bz, Wr, br, Wh, bh,
                                   Whead, bhead, Ha, Hb, RHT, bar, out);
}